// Round 10
// baseline (412.942 us; speedup 1.0000x reference)
//
#include <hip/hip_runtime.h>
#include <math.h>

#define HW       50176
#define W_IMG    224
#define S_FRAMES 8
#define NT       2048
#define NJCH     196
#define JCH      256     // 196*256 = 50176, one 256-tile per chunk
#define NID      (7 * NT)

// ---------------- static device scratch ---------------------------------------
__device__ unsigned           g_hist1[65536];
__device__ unsigned           g_hist2[65536];
__device__ unsigned           g_scalars[16];   // [0]=binB [1]=cntAboveBin [2]=threshT [4]=compactCnt
__device__ unsigned long long g_keys[4096];
__device__ int                g_matches[S_FRAMES * NT];
__device__ float4             g_ref[NT];
__device__ float              g_pd[NJCH * NID];   // [jc][id] transposed: coalesced writes
__device__ int                g_pj[NJCH * NID];

__device__ __forceinline__ unsigned ordered_u32(float f) {
  unsigned u = __float_as_uint(f);
  return (u & 0x80000000u) ? ~u : (u | 0x80000000u);
}

// ---------------- top-k: radix select + bitonic sort --------------------------
__global__ void zero_kernel() {
  int i = blockIdx.x * blockDim.x + threadIdx.x;
  if (i < 65536) { g_hist1[i] = 0u; g_hist2[i] = 0u; }
  if (i < 4096)  g_keys[i] = 0ULL;
  if (i < 16)    g_scalars[i] = 0u;
}

__global__ void hist1_kernel(const float* __restrict__ conf) {
  int i = blockIdx.x * blockDim.x + threadIdx.x;
  if (i < HW) atomicAdd(&g_hist1[ordered_u32(conf[i]) >> 16], 1u);
}

// 1024 threads, 64 bins each; LDS suffix-scan; per-thread descending bin walk.
__global__ __launch_bounds__(1024) void scan1_kernel() {
  __shared__ unsigned ssum[1024];
  int t = threadIdx.x;
  unsigned mysum = 0;
  for (int b = 0; b < 64; ++b) mysum += g_hist1[t * 64 + b];
  ssum[t] = mysum;
  __syncthreads();
  for (int off = 1; off < 1024; off <<= 1) {
    unsigned v = (t + off < 1024) ? ssum[t + off] : 0u;
    __syncthreads();
    ssum[t] += v;
    __syncthreads();
  }
  unsigned run = ssum[t] - mysum;   // count of elements in bins above my range
  for (int b = 63; b >= 0; --b) {
    unsigned h = g_hist1[t * 64 + b];
    if (run < NT && run + h >= NT) { g_scalars[0] = (unsigned)(t * 64 + b); g_scalars[1] = run; }
    run += h;
  }
}

__global__ void hist2_kernel(const float* __restrict__ conf) {
  int i = blockIdx.x * blockDim.x + threadIdx.x;
  if (i < HW) {
    unsigned ou = ordered_u32(conf[i]);
    if ((ou >> 16) == g_scalars[0]) atomicAdd(&g_hist2[ou & 0xFFFFu], 1u);
  }
}

__global__ __launch_bounds__(1024) void scan2_kernel() {
  __shared__ unsigned ssum[1024];
  int t = threadIdx.x;
  unsigned R = NT - g_scalars[1];
  unsigned mysum = 0;
  for (int b = 0; b < 64; ++b) mysum += g_hist2[t * 64 + b];
  ssum[t] = mysum;
  __syncthreads();
  for (int off = 1; off < 1024; off <<= 1) {
    unsigned v = (t + off < 1024) ? ssum[t + off] : 0u;
    __syncthreads();
    ssum[t] += v;
    __syncthreads();
  }
  unsigned run = ssum[t] - mysum;
  for (int b = 63; b >= 0; --b) {
    unsigned h = g_hist2[t * 64 + b];
    if (run < R && run + h >= R) g_scalars[2] = (g_scalars[0] << 16) | (unsigned)(t * 64 + b);
    run += h;
  }
}

__global__ void compact_kernel(const float* __restrict__ conf) {
  int i = blockIdx.x * blockDim.x + threadIdx.x;
  if (i < HW) {
    unsigned ou = ordered_u32(conf[i]);
    if (ou >= g_scalars[2]) {
      unsigned pos = atomicAdd(&g_scalars[4], 1u);
      if (pos < 4096) g_keys[pos] = ((unsigned long long)ou << 32) | (unsigned long long)(0xFFFFFFFFu - (unsigned)i);
    }
  }
}

__global__ __launch_bounds__(1024) void sortwrite_kernel(const float* __restrict__ pts) {
  __shared__ unsigned long long sk[4096];
  int t = threadIdx.x;
  for (int i = t; i < 4096; i += 1024) sk[i] = ~g_keys[i];  // ascending == key desc
  for (unsigned k = 2; k <= 4096; k <<= 1) {
    for (unsigned j = k >> 1; j > 0; j >>= 1) {
      __syncthreads();
      for (unsigned i = t; i < 4096; i += 1024) {
        unsigned ixj = i ^ j;
        if (ixj > i) {
          unsigned long long a = sk[i], b = sk[ixj];
          bool up = ((i & k) == 0);
          if (up ? (a > b) : (a < b)) { sk[i] = b; sk[ixj] = a; }
        }
      }
    }
  }
  __syncthreads();
  for (int i = t; i < NT; i += 1024) {
    unsigned long long key = ~sk[i];
    unsigned idx = 0xFFFFFFFFu - (unsigned)(key & 0xFFFFFFFFu);
    g_matches[i] = (int)idx;
    const float* p = pts + (size_t)idx * 3;
    float x = p[0], y = p[1], z = p[2];
    g_ref[i] = make_float4(x, y, z, fmaf(x, x, fmaf(y, y, z * z)));
  }
}

// ---------------- matching: brute-force 3D NN argmin, IPT=4 -------------------
__global__ __launch_bounds__(256) void match_kernel(const float* __restrict__ pts) {
  __shared__ float4 tile[256];
  int jc = blockIdx.x;            // 0..195
  int ic = blockIdx.y;            // 0..1 (1024 refs per block)
  int f  = blockIdx.z;            // 0..6 -> frame f+1
  int t  = threadIdx.x;
  int ib = ic * 1024 + t;

  float4 r0 = g_ref[ib];
  float4 r1 = g_ref[ib + 256];
  float4 r2 = g_ref[ib + 512];
  float4 r3 = g_ref[ib + 768];
  float dmin0 = INFINITY, dmin1 = INFINITY, dmin2 = INFINITY, dmin3 = INFINITY;
  int   jmin0 = 0, jmin1 = 0, jmin2 = 0, jmin3 = 0;

  const float* fp = pts + (size_t)(f + 1) * HW * 3;
  int jb = jc * JCH;
  const float* p = fp + (size_t)(jb + t) * 3;
  float x = p[0], y = p[1], z = p[2];
  float sq = fmaf(x, x, fmaf(y, y, z * z));
  tile[t] = make_float4(-2.0f * x, -2.0f * y, -2.0f * z, sq);
  __syncthreads();
#pragma unroll 4
  for (int u = 0; u < 256; ++u) {
    float4 q = tile[u];
    int ju = jb + u;
    // d' = fp_sq - 2*dot  (ref_sq dropped: constant per i)
    float d0 = fmaf(q.x, r0.x, fmaf(q.y, r0.y, fmaf(q.z, r0.z, q.w)));
    float d1 = fmaf(q.x, r1.x, fmaf(q.y, r1.y, fmaf(q.z, r1.z, q.w)));
    float d2 = fmaf(q.x, r2.x, fmaf(q.y, r2.y, fmaf(q.z, r2.z, q.w)));
    float d3 = fmaf(q.x, r3.x, fmaf(q.y, r3.y, fmaf(q.z, r3.z, q.w)));
    if (d0 < dmin0) { dmin0 = d0; jmin0 = ju; }
    if (d1 < dmin1) { dmin1 = d1; jmin1 = ju; }
    if (d2 < dmin2) { dmin2 = d2; jmin2 = ju; }
    if (d3 < dmin3) { dmin3 = d3; jmin3 = ju; }
  }
  // transposed layout [jc][id]: consecutive threads -> consecutive addresses
  int idb = f * NT + ib;
  g_pd[jc * NID + idb]       = dmin0;  g_pj[jc * NID + idb]       = jmin0;
  g_pd[jc * NID + idb + 256] = dmin1;  g_pj[jc * NID + idb + 256] = jmin1;
  g_pd[jc * NID + idb + 512] = dmin2;  g_pj[jc * NID + idb + 512] = jmin2;
  g_pd[jc * NID + idb + 768] = dmin3;  g_pj[jc * NID + idb + 768] = jmin3;
}

__global__ void reduce_kernel() {
  int id = blockIdx.x * blockDim.x + threadIdx.x;   // 0..7*2048-1
  if (id >= NID) return;
  float dmin = INFINITY;
  int   jmin = 0;
  for (int c = 0; c < NJCH; ++c) {                  // chunks ascend in j; coalesced reads
    float d = g_pd[c * NID + id];
    int   j = g_pj[c * NID + id];
    if (d < dmin) { dmin = d; jmin = j; }           // strict < keeps earliest j
  }
  int f = id / NT, i = id % NT;
  g_matches[(f + 1) * NT + i] = jmin;
}

// ---------------- per-track DLT + Jacobi eigensolve + metrics -----------------
__global__ __launch_bounds__(64) void solve_kernel(const float* __restrict__ conf, const float* __restrict__ intr,
                             const float* __restrict__ w2cs, float* __restrict__ out) {
  int i = blockIdx.x * blockDim.x + threadIdx.x;
  if (i >= NT) return;

  float A1[10] = {0}, A2[10] = {0};
  float tnx[8], tny[8], cf[8];
  float x0 = 0.f, y0 = 0.f;

#pragma unroll 1
  for (int s = 0; s < S_FRAMES; ++s) {
    int m = g_matches[s * NT + i];
    float xs = (float)(m % W_IMG);
    float ys = (float)(m / W_IMG);
    float c  = conf[s * HW + m];
    float fx = intr[s * 9 + 0], fy = intr[s * 9 + 4];
    float cx = intr[s * 9 + 2], cy = intr[s * 9 + 5];
    float tx = (xs - cx) / fx;
    float ty = (ys - cy) / fy;
    float w  = (c - 3.0f) + 0.5f;
    const float* P = w2cs + s * 16;
    float r1[4], r2[4];
#pragma unroll
    for (int k = 0; k < 4; ++k) {
      r1[k] = (tx * P[8 + k] - P[k])     * w;
      r2[k] = (ty * P[8 + k] - P[4 + k]) * w;
    }
    int idx = 0;
#pragma unroll
    for (int a = 0; a < 4; ++a)
#pragma unroll
      for (int b = a; b < 4; ++b) {
        A1[idx] += r1[a] * r1[b];
        A2[idx] += r2[a] * r2[b];
        ++idx;
      }
    tnx[s] = tx; tny[s] = ty; cf[s] = c;
    if (s == 0) { x0 = xs; y0 = ys; }
  }

  double a[4][4], V[4][4];
  {
    int idx = 0;
#pragma unroll
    for (int p = 0; p < 4; ++p)
#pragma unroll
      for (int q = p; q < 4; ++q) {
        double v = (double)(A1[idx] + A2[idx]);
        a[p][q] = v; a[q][p] = v; ++idx;
      }
#pragma unroll
    for (int p = 0; p < 4; ++p)
#pragma unroll
      for (int q = 0; q < 4; ++q) V[p][q] = (p == q) ? 1.0 : 0.0;
  }

  // 6 cyclic sweeps; sweep loop kept rolled (#pragma unroll 1) so code stays
  // ~one sweep body (~10 KB) and fits I$ — full unroll was I-fetch-bound (148us).
  // Inner rotation loops stay unrolled: static indexing avoids scratch (rule #20).
#pragma unroll 1
  for (int sweep = 0; sweep < 6; ++sweep) {
#pragma unroll
    for (int p = 0; p < 3; ++p)
#pragma unroll
      for (int q = p + 1; q < 4; ++q) {
        double apq = a[p][q];
        if (fabs(apq) <= 1e-40) continue;
        double theta = (a[q][q] - a[p][p]) / (2.0 * apq);
        double tt  = copysign(1.0, theta) / (fabs(theta) + sqrt(theta * theta + 1.0));
        double cth = 1.0 / sqrt(tt * tt + 1.0);
        double sth = tt * cth;
#pragma unroll
        for (int k = 0; k < 4; ++k) {
          double akp = a[p][k], akq = a[q][k];
          a[p][k] = cth * akp - sth * akq;
          a[q][k] = sth * akp + cth * akq;
        }
#pragma unroll
        for (int k = 0; k < 4; ++k) {
          double akp = a[k][p], akq = a[k][q];
          a[k][p] = cth * akp - sth * akq;
          a[k][q] = sth * akp + cth * akq;
        }
#pragma unroll
        for (int k = 0; k < 4; ++k) {
          double vkp = V[k][p], vkq = V[k][q];
          V[k][p] = cth * vkp - sth * vkq;
          V[k][q] = sth * vkp + cth * vkq;
        }
      }
  }

  int kmin = 0; double emin = a[0][0];
#pragma unroll
  for (int k = 1; k < 4; ++k) if (a[k][k] < emin) { emin = a[k][k]; kmin = k; }

  double vsel[4];
#pragma unroll
  for (int r = 0; r < 4; ++r) {
    double x = V[r][0];
    if (kmin == 1) x = V[r][1];
    if (kmin == 2) x = V[r][2];
    if (kmin == 3) x = V[r][3];
    vsel[r] = x;
  }
  float v0 = (float)vsel[0], v1 = (float)vsel[1], v2 = (float)vsel[2], v3 = (float)vsel[3];
  float denom = (fabsf(v3) < 1e-8f) ? 1e-8f : v3;
  float X0 = v0 / denom, X1 = v1 / denom, X2 = v2 / denom;

  int innum = 0; float wsum = 0.f; float u0x = 0.f, u0y = 0.f;
#pragma unroll 1
  for (int s = 0; s < S_FRAMES; ++s) {
    const float* P = w2cs + s * 16;
    float Xc0 = fmaf(P[2],  X2, fmaf(P[1], X1, P[0] * X0)) + P[3];
    float Xc1 = fmaf(P[6],  X2, fmaf(P[5], X1, P[4] * X0)) + P[7];
    float z   = fmaf(P[10], X2, fmaf(P[9], X1, P[8] * X0)) + P[11];
    if (fabsf(z) < 1e-6f) z = 1e-6f;
    float ux = Xc0 / z, uy = Xc1 / z;
    float dx = ux - tnx[s], dy = uy - tny[s];
    float e = sqrtf(dx * dx + dy * dy);
    bool in = e < 0.01f;
    if (in) { innum++; wsum += cf[s]; }
    if (s == 0) { u0x = ux; u0y = uy; }
  }
  float fx0 = intr[0], fy0 = intr[4], cx0 = intr[2], cy0 = intr[5];
  float posx = fmaf(u0x, fx0, cx0), posy = fmaf(u0y, fy0, cy0);
  float dxp = posx - x0, dyp = posy - y0;
  float epx = sqrtf(dxp * dxp + dyp * dyp);
  int mask = (epx < 1.5f && innum > 4) ? 1 : 0;
  float pconf = wsum / (float)((innum > 1) ? innum : 1);
  if (innum < 4) pconf = 1.0f;

  out[3 * i + 0] = X0;
  out[3 * i + 1] = X1;
  out[3 * i + 2] = X2;
  out[6144 + i]  = pconf;
  out[8192 + i]  = (float)mask;
  out[10240 + i] = (float)innum;
}

// ---------------- launcher ----------------------------------------------------
extern "C" void kernel_launch(void* const* d_in, const int* in_sizes, int n_in,
                              void* d_out, int out_size, void* d_ws, size_t ws_size,
                              hipStream_t stream) {
  const float* pts  = (const float*)d_in[0];
  const float* conf = (const float*)d_in[1];
  const float* intr = (const float*)d_in[2];
  const float* w2cs = (const float*)d_in[3];
  float* out = (float*)d_out;

  zero_kernel   <<<256, 256, 0, stream>>>();
  hist1_kernel  <<<196, 256, 0, stream>>>(conf);
  scan1_kernel  <<<1,  1024, 0, stream>>>();
  hist2_kernel  <<<196, 256, 0, stream>>>(conf);
  scan2_kernel  <<<1,  1024, 0, stream>>>();
  compact_kernel<<<196, 256, 0, stream>>>(conf);
  sortwrite_kernel<<<1, 1024, 0, stream>>>(pts);
  match_kernel  <<<dim3(NJCH, 2, 7), 256, 0, stream>>>(pts);
  reduce_kernel <<<56,  256, 0, stream>>>();
  solve_kernel  <<<32,  64, 0, stream>>>(conf, intr, w2cs, out);
}

// Round 12
// 364.030 us; speedup vs baseline: 1.1344x; 1.1344x over previous
//
#include <hip/hip_runtime.h>
#include <math.h>

#define HW       50176
#define W_IMG    224
#define S_FRAMES 8
#define NT       2048
#define NJCH     196
#define JCH      256     // 196*256 = 50176, one 256-tile per chunk
#define NID      (7 * NT)

// ---------------- static device scratch ---------------------------------------
__device__ __align__(16) unsigned g_hist1[65536];
__device__ __align__(16) unsigned g_hist2[65536];
__device__ unsigned           g_scalars[16];   // [0]=binB [1]=cntAboveBin [2]=threshT [4]=compactCnt
__device__ unsigned long long g_keys[4096];
__device__ int                g_matches[S_FRAMES * NT];
__device__ float4             g_ref[NT];
__device__ float              g_pd[NJCH * NID];   // [jc][id] transposed: coalesced writes
__device__ int                g_pj[NJCH * NID];

__device__ __forceinline__ unsigned ordered_u32(float f) {
  unsigned u = __float_as_uint(f);
  return (u & 0x80000000u) ? ~u : (u | 0x80000000u);
}

// ---------------- top-k: radix select + bitonic sort --------------------------
__global__ void zero_kernel() {
  int i = blockIdx.x * blockDim.x + threadIdx.x;
  if (i < 65536) { g_hist1[i] = 0u; g_hist2[i] = 0u; }
  if (i < 4096)  g_keys[i] = 0ULL;
  if (i < 16)    g_scalars[i] = 0u;
}

__global__ void hist1_kernel(const float* __restrict__ conf) {
  int i = blockIdx.x * blockDim.x + threadIdx.x;
  if (i < HW) atomicAdd(&g_hist1[ordered_u32(conf[i]) >> 16], 1u);
}

// 1024 threads x 64 bins; uint4 loads (was 128 stride-256B scalar loads);
// LDS suffix-scan; fully-unrolled descending walk reuses the loaded registers.
__global__ __launch_bounds__(1024) void scan1_kernel() {
  __shared__ unsigned ssum[1024];
  int t = threadIdx.x;
  uint4 hv[16];
  const uint4* h4 = reinterpret_cast<const uint4*>(&g_hist1[t * 64]);
  unsigned mysum = 0;
#pragma unroll
  for (int b = 0; b < 16; ++b) { hv[b] = h4[b]; mysum += hv[b].x + hv[b].y + hv[b].z + hv[b].w; }
  ssum[t] = mysum;
  __syncthreads();
  for (int off = 1; off < 1024; off <<= 1) {
    unsigned v = (t + off < 1024) ? ssum[t + off] : 0u;
    __syncthreads();
    ssum[t] += v;
    __syncthreads();
  }
  unsigned run = ssum[t] - mysum;   // count of elements in bins above my range
#define STEP1(H, B) { unsigned h = (H); \
    if (run < NT && run + h >= NT) { g_scalars[0] = (unsigned)(t * 64 + (B)); g_scalars[1] = run; } \
    run += h; }
#pragma unroll
  for (int b4 = 15; b4 >= 0; --b4) {
    uint4 v = hv[b4];
    STEP1(v.w, b4 * 4 + 3); STEP1(v.z, b4 * 4 + 2); STEP1(v.y, b4 * 4 + 1); STEP1(v.x, b4 * 4 + 0);
  }
#undef STEP1
}

__global__ void hist2_kernel(const float* __restrict__ conf) {
  int i = blockIdx.x * blockDim.x + threadIdx.x;
  if (i < HW) {
    unsigned ou = ordered_u32(conf[i]);
    if ((ou >> 16) == g_scalars[0]) atomicAdd(&g_hist2[ou & 0xFFFFu], 1u);
  }
}

__global__ __launch_bounds__(1024) void scan2_kernel() {
  __shared__ unsigned ssum[1024];
  int t = threadIdx.x;
  unsigned R = NT - g_scalars[1];
  uint4 hv[16];
  const uint4* h4 = reinterpret_cast<const uint4*>(&g_hist2[t * 64]);
  unsigned mysum = 0;
#pragma unroll
  for (int b = 0; b < 16; ++b) { hv[b] = h4[b]; mysum += hv[b].x + hv[b].y + hv[b].z + hv[b].w; }
  ssum[t] = mysum;
  __syncthreads();
  for (int off = 1; off < 1024; off <<= 1) {
    unsigned v = (t + off < 1024) ? ssum[t + off] : 0u;
    __syncthreads();
    ssum[t] += v;
    __syncthreads();
  }
  unsigned run = ssum[t] - mysum;
#define STEP2(H, B) { unsigned h = (H); \
    if (run < R && run + h >= R) g_scalars[2] = (g_scalars[0] << 16) | (unsigned)(t * 64 + (B)); \
    run += h; }
#pragma unroll
  for (int b4 = 15; b4 >= 0; --b4) {
    uint4 v = hv[b4];
    STEP2(v.w, b4 * 4 + 3); STEP2(v.z, b4 * 4 + 2); STEP2(v.y, b4 * 4 + 1); STEP2(v.x, b4 * 4 + 0);
  }
#undef STEP2
}

__global__ void compact_kernel(const float* __restrict__ conf) {
  int i = blockIdx.x * blockDim.x + threadIdx.x;
  if (i < HW) {
    unsigned ou = ordered_u32(conf[i]);
    if (ou >= g_scalars[2]) {
      unsigned pos = atomicAdd(&g_scalars[4], 1u);
      if (pos < 4096) g_keys[pos] = ((unsigned long long)ou << 32) | (unsigned long long)(0xFFFFFFFFu - (unsigned)i);
    }
  }
}

__global__ __launch_bounds__(1024) void sortwrite_kernel(const float* __restrict__ pts) {
  __shared__ unsigned long long sk[4096];
  int t = threadIdx.x;
  for (int i = t; i < 4096; i += 1024) sk[i] = ~g_keys[i];  // ascending == key desc
  for (unsigned k = 2; k <= 4096; k <<= 1) {
    for (unsigned j = k >> 1; j > 0; j >>= 1) {
      __syncthreads();
      for (unsigned i = t; i < 4096; i += 1024) {
        unsigned ixj = i ^ j;
        if (ixj > i) {
          unsigned long long a = sk[i], b = sk[ixj];
          bool up = ((i & k) == 0);
          if (up ? (a > b) : (a < b)) { sk[i] = b; sk[ixj] = a; }
        }
      }
    }
  }
  __syncthreads();
  for (int i = t; i < NT; i += 1024) {
    unsigned long long key = ~sk[i];
    unsigned idx = 0xFFFFFFFFu - (unsigned)(key & 0xFFFFFFFFu);
    g_matches[i] = (int)idx;
    const float* p = pts + (size_t)idx * 3;
    float x = p[0], y = p[1], z = p[2];
    g_ref[i] = make_float4(x, y, z, fmaf(x, x, fmaf(y, y, z * z)));
  }
}

// ---------------- matching: brute-force 3D NN argmin, IPT=4 -------------------
__global__ __launch_bounds__(256) void match_kernel(const float* __restrict__ pts) {
  __shared__ float4 tile[256];
  int jc = blockIdx.x;            // 0..195
  int ic = blockIdx.y;            // 0..1 (1024 refs per block)
  int f  = blockIdx.z;            // 0..6 -> frame f+1
  int t  = threadIdx.x;
  int ib = ic * 1024 + t;

  float4 r0 = g_ref[ib];
  float4 r1 = g_ref[ib + 256];
  float4 r2 = g_ref[ib + 512];
  float4 r3 = g_ref[ib + 768];
  float dmin0 = INFINITY, dmin1 = INFINITY, dmin2 = INFINITY, dmin3 = INFINITY;
  int   jmin0 = 0, jmin1 = 0, jmin2 = 0, jmin3 = 0;

  const float* fp = pts + (size_t)(f + 1) * HW * 3;
  int jb = jc * JCH;
  const float* p = fp + (size_t)(jb + t) * 3;
  float x = p[0], y = p[1], z = p[2];
  float sq = fmaf(x, x, fmaf(y, y, z * z));
  tile[t] = make_float4(-2.0f * x, -2.0f * y, -2.0f * z, sq);
  __syncthreads();
#pragma unroll 4
  for (int u = 0; u < 256; ++u) {
    float4 q = tile[u];
    int ju = jb + u;
    // d' = fp_sq - 2*dot  (ref_sq dropped: constant per i)
    float d0 = fmaf(q.x, r0.x, fmaf(q.y, r0.y, fmaf(q.z, r0.z, q.w)));
    float d1 = fmaf(q.x, r1.x, fmaf(q.y, r1.y, fmaf(q.z, r1.z, q.w)));
    float d2 = fmaf(q.x, r2.x, fmaf(q.y, r2.y, fmaf(q.z, r2.z, q.w)));
    float d3 = fmaf(q.x, r3.x, fmaf(q.y, r3.y, fmaf(q.z, r3.z, q.w)));
    if (d0 < dmin0) { dmin0 = d0; jmin0 = ju; }
    if (d1 < dmin1) { dmin1 = d1; jmin1 = ju; }
    if (d2 < dmin2) { dmin2 = d2; jmin2 = ju; }
    if (d3 < dmin3) { dmin3 = d3; jmin3 = ju; }
  }
  // transposed layout [jc][id]: consecutive threads -> consecutive addresses
  int idb = f * NT + ib;
  g_pd[jc * NID + idb]       = dmin0;  g_pj[jc * NID + idb]       = jmin0;
  g_pd[jc * NID + idb + 256] = dmin1;  g_pj[jc * NID + idb + 256] = jmin1;
  g_pd[jc * NID + idb + 512] = dmin2;  g_pj[jc * NID + idb + 512] = jmin2;
  g_pd[jc * NID + idb + 768] = dmin3;  g_pj[jc * NID + idb + 768] = jmin3;
}

__global__ void reduce_kernel() {
  int id = blockIdx.x * blockDim.x + threadIdx.x;   // 0..7*2048-1
  if (id >= NID) return;
  float dmin = INFINITY;
  int   jmin = 0;
  for (int c = 0; c < NJCH; ++c) {                  // chunks ascend in j; coalesced reads
    float d = g_pd[c * NID + id];
    int   j = g_pj[c * NID + id];
    if (d < dmin) { dmin = d; jmin = j; }           // strict < keeps earliest j
  }
  int f = id / NT, i = id % NT;
  g_matches[(f + 1) * NT + i] = jmin;
}

// ---------------- per-track DLT + Jacobi (all-scalar, register-resident) ------
// Rule #20 fix: R10 showed VGPR_Count=64 with f64 a[4][4]+V[4][4] arrays ->
// they lived in scratch; VALUBusy 0.012% = serial scratch-latency chain.
// Symmetric Jacobi on 10 named triangle doubles + 16 named V doubles.
#define JROT(APP, APQ, AQQ, AK1P, AK1Q, AK2P, AK2Q, VA, VB, VC, VD, VE, VF, VG, VH) \
  { double apq_ = APQ;                                                              \
    if (fabs(apq_) > 1e-40) {                                                       \
      double th_ = (AQQ - APP) / (2.0 * apq_);                                      \
      double t_  = copysign(1.0, th_) / (fabs(th_) + sqrt(th_ * th_ + 1.0));        \
      double c_  = 1.0 / sqrt(t_ * t_ + 1.0);                                       \
      double s_  = t_ * c_;                                                         \
      APP -= t_ * apq_;  AQQ += t_ * apq_;  APQ = 0.0;                              \
      double x_;                                                                    \
      x_ = AK1P; AK1P = c_ * x_ - s_ * AK1Q; AK1Q = s_ * x_ + c_ * AK1Q;            \
      x_ = AK2P; AK2P = c_ * x_ - s_ * AK2Q; AK2Q = s_ * x_ + c_ * AK2Q;            \
      x_ = VA; VA = c_ * x_ - s_ * VB; VB = s_ * x_ + c_ * VB;                      \
      x_ = VC; VC = c_ * x_ - s_ * VD; VD = s_ * x_ + c_ * VD;                      \
      x_ = VE; VE = c_ * x_ - s_ * VF; VF = s_ * x_ + c_ * VF;                      \
      x_ = VG; VG = c_ * x_ - s_ * VH; VH = s_ * x_ + c_ * VH;                      \
    } }

__global__ __launch_bounds__(64) void solve_kernel(const float* __restrict__ conf, const float* __restrict__ intr,
                             const float* __restrict__ w2cs, float* __restrict__ out) {
  int i = blockIdx.x * blockDim.x + threadIdx.x;
  if (i >= NT) return;

  float A1[10] = {0}, A2[10] = {0};
  float tnx[8], tny[8], cf[8];
  float x0 = 0.f, y0 = 0.f;

#pragma unroll 1
  for (int s = 0; s < S_FRAMES; ++s) {
    int m = g_matches[s * NT + i];
    float xs = (float)(m % W_IMG);
    float ys = (float)(m / W_IMG);
    float c  = conf[s * HW + m];
    float fx = intr[s * 9 + 0], fy = intr[s * 9 + 4];
    float cx = intr[s * 9 + 2], cy = intr[s * 9 + 5];
    float tx = (xs - cx) / fx;
    float ty = (ys - cy) / fy;
    float w  = (c - 3.0f) + 0.5f;
    const float* P = w2cs + s * 16;
    float r1[4], r2[4];
#pragma unroll
    for (int k = 0; k < 4; ++k) {
      r1[k] = (tx * P[8 + k] - P[k])     * w;
      r2[k] = (ty * P[8 + k] - P[4 + k]) * w;
    }
    int idx = 0;
#pragma unroll
    for (int a = 0; a < 4; ++a)
#pragma unroll
      for (int b = a; b < 4; ++b) {
        A1[idx] += r1[a] * r1[b];
        A2[idx] += r2[a] * r2[b];
        ++idx;
      }
    tnx[s] = tx; tny[s] = ty; cf[s] = c;
    if (s == 0) { x0 = xs; y0 = ys; }
  }

  // upper triangle of AtA = A1 + A2 (f32 sum, like reference), as named f64 scalars
  double a00 = (double)(A1[0] + A2[0]), a01 = (double)(A1[1] + A2[1]);
  double a02 = (double)(A1[2] + A2[2]), a03 = (double)(A1[3] + A2[3]);
  double a11 = (double)(A1[4] + A2[4]), a12 = (double)(A1[5] + A2[5]);
  double a13 = (double)(A1[6] + A2[6]), a22 = (double)(A1[7] + A2[7]);
  double a23 = (double)(A1[8] + A2[8]), a33 = (double)(A1[9] + A2[9]);
  double v00 = 1.0, v01 = 0.0, v02 = 0.0, v03 = 0.0;
  double v10 = 0.0, v11 = 1.0, v12 = 0.0, v13 = 0.0;
  double v20 = 0.0, v21 = 0.0, v22 = 1.0, v23 = 0.0;
  double v30 = 0.0, v31 = 0.0, v32 = 0.0, v33 = 1.0;

#pragma unroll 1
  for (int sweep = 0; sweep < 6; ++sweep) {
    // (p,q)=(0,1): others k=2 (a02,a12), k=3 (a03,a13); V cols 0,1
    JROT(a00, a01, a11, a02, a12, a03, a13, v00, v01, v10, v11, v20, v21, v30, v31)
    // (0,2): k=1 (a01,a12), k=3 (a03,a23); V cols 0,2
    JROT(a00, a02, a22, a01, a12, a03, a23, v00, v02, v10, v12, v20, v22, v30, v32)
    // (0,3): k=1 (a01,a13), k=2 (a02,a23); V cols 0,3
    JROT(a00, a03, a33, a01, a13, a02, a23, v00, v03, v10, v13, v20, v23, v30, v33)
    // (1,2): k=0 (a01,a02), k=3 (a13,a23); V cols 1,2
    JROT(a11, a12, a22, a01, a02, a13, a23, v01, v02, v11, v12, v21, v22, v31, v32)
    // (1,3): k=0 (a01,a03), k=2 (a12,a23); V cols 1,3
    JROT(a11, a13, a33, a01, a03, a12, a23, v01, v03, v11, v13, v21, v23, v31, v33)
    // (2,3): k=0 (a02,a03), k=1 (a12,a13); V cols 2,3
    JROT(a22, a23, a33, a02, a03, a12, a13, v02, v03, v12, v13, v22, v23, v32, v33)
  }

  int kmin = 0; double emin = a00;
  if (a11 < emin) { emin = a11; kmin = 1; }
  if (a22 < emin) { emin = a22; kmin = 2; }
  if (a33 < emin) { emin = a33; kmin = 3; }

  double w0 = (kmin == 1) ? v01 : (kmin == 2) ? v02 : (kmin == 3) ? v03 : v00;
  double w1 = (kmin == 1) ? v11 : (kmin == 2) ? v12 : (kmin == 3) ? v13 : v10;
  double w2 = (kmin == 1) ? v21 : (kmin == 2) ? v22 : (kmin == 3) ? v23 : v20;
  double w3 = (kmin == 1) ? v31 : (kmin == 2) ? v32 : (kmin == 3) ? v33 : v30;

  float f0 = (float)w0, f1 = (float)w1, f2 = (float)w2, f3 = (float)w3;
  float denom = (fabsf(f3) < 1e-8f) ? 1e-8f : f3;
  float X0 = f0 / denom, X1 = f1 / denom, X2 = f2 / denom;

  int innum = 0; float wsum = 0.f; float u0x = 0.f, u0y = 0.f;
#pragma unroll 1
  for (int s = 0; s < S_FRAMES; ++s) {
    const float* P = w2cs + s * 16;
    float Xc0 = fmaf(P[2],  X2, fmaf(P[1], X1, P[0] * X0)) + P[3];
    float Xc1 = fmaf(P[6],  X2, fmaf(P[5], X1, P[4] * X0)) + P[7];
    float z   = fmaf(P[10], X2, fmaf(P[9], X1, P[8] * X0)) + P[11];
    if (fabsf(z) < 1e-6f) z = 1e-6f;
    float ux = Xc0 / z, uy = Xc1 / z;
    float dx = ux - tnx[s], dy = uy - tny[s];
    float e = sqrtf(dx * dx + dy * dy);
    bool in = e < 0.01f;
    if (in) { innum++; wsum += cf[s]; }
    if (s == 0) { u0x = ux; u0y = uy; }
  }
  float fx0 = intr[0], fy0 = intr[4], cx0 = intr[2], cy0 = intr[5];
  float posx = fmaf(u0x, fx0, cx0), posy = fmaf(u0y, fy0, cy0);
  float dxp = posx - x0, dyp = posy - y0;
  float epx = sqrtf(dxp * dxp + dyp * dyp);
  int mask = (epx < 1.5f && innum > 4) ? 1 : 0;
  float pconf = wsum / (float)((innum > 1) ? innum : 1);
  if (innum < 4) pconf = 1.0f;

  out[3 * i + 0] = X0;
  out[3 * i + 1] = X1;
  out[3 * i + 2] = X2;
  out[6144 + i]  = pconf;
  out[8192 + i]  = (float)mask;
  out[10240 + i] = (float)innum;
}

// ---------------- launcher ----------------------------------------------------
extern "C" void kernel_launch(void* const* d_in, const int* in_sizes, int n_in,
                              void* d_out, int out_size, void* d_ws, size_t ws_size,
                              hipStream_t stream) {
  const float* pts  = (const float*)d_in[0];
  const float* conf = (const float*)d_in[1];
  const float* intr = (const float*)d_in[2];
  const float* w2cs = (const float*)d_in[3];
  float* out = (float*)d_out;

  zero_kernel   <<<256, 256, 0, stream>>>();
  hist1_kernel  <<<196, 256, 0, stream>>>(conf);
  scan1_kernel  <<<1,  1024, 0, stream>>>();
  hist2_kernel  <<<196, 256, 0, stream>>>(conf);
  scan2_kernel  <<<1,  1024, 0, stream>>>();
  compact_kernel<<<196, 256, 0, stream>>>(conf);
  sortwrite_kernel<<<1, 1024, 0, stream>>>(pts);
  match_kernel  <<<dim3(NJCH, 2, 7), 256, 0, stream>>>(pts);
  reduce_kernel <<<56,  256, 0, stream>>>();
  solve_kernel  <<<32,  64, 0, stream>>>(conf, intr, w2cs, out);
}